// Round 15
// baseline (288.713 us; speedup 1.0000x reference)
//
#include <hip/hip_runtime.h>

constexpr int N    = 8192;
constexpr int NPG  = 512;   // nodes per graph
constexpr int NG   = 16;
constexpr int KNN  = 80;
constexpr int F0   = 6;
constexpr int HID  = 128;
constexpr int H6   = 768;
constexpr int RPB  = 16;    // rows per combine block
constexpr int BPGR = NPG / RPB;  // combine blocks per graph = 32

__device__ __forceinline__ float leaky(float v) { return v > 0.0f ? v : 0.01f * v; }

__device__ __forceinline__ int lanes_below(unsigned long long m) {
    return __builtin_amdgcn_mbcnt_hi((unsigned)(m >> 32),
           __builtin_amdgcn_mbcnt_lo((unsigned)m, 0));
}

// wave-sum of a per-lane count in [0,8] via 4 ballots (result uniform)
__device__ __forceinline__ int wave_count_sum(int c) {
    int total = 0;
    #pragma unroll
    for (int b = 0; b < 4; b++)
        total += (int)__popcll(__ballot((c >> b) & 1)) << b;
    return total;
}

// ---------------------------------------------------------------------------
// KNN, wave-per-target (see R2 notes): exact rank-79 threshold via 32-step
// binary search on monotonic-mapped d2, tie-break by node order, 128-elem
// bitonic sort for output order.
// ---------------------------------------------------------------------------
__global__ __launch_bounds__(256) void knn_kernel(const float* __restrict__ x,
                                                  int* __restrict__ nbr) {
    constexpr int BPG = 128;               // blocks per graph (4 targets each)
    const int tid  = threadIdx.x;
    const int lane = tid & 63;
    const int wv   = tid >> 6;
    const int base = (blockIdx.x / BPG) << 9;
    const int t    = base + (blockIdx.x & (BPG - 1)) * 4 + wv;
    const int tl   = t - base;

    __shared__ float px[512], py[512], pz[512], pw[512];
    __shared__ unsigned long long skey[4 * 128];

    for (int j = tid; j < 512; j += 256) {
        const float* row = x + (size_t)(base + j) * F0;
        const float2 ra = *(const float2*)(row);
        const float2 rb = *(const float2*)(row + 2);
        px[j] = ra.x; py[j] = ra.y; pz[j] = rb.x; pw[j] = rb.y;
    }
    __syncthreads();

    const float tx = px[tl], ty = py[tl], tz = pz[tl], tw = pw[tl];
    const float sqt = tx*tx + ty*ty + tz*tz + tw*tw;

    unsigned d2m[8];
    #pragma unroll
    for (int j = 0; j < 8; j++) {
        const int node = j * 64 + lane;
        const float jx = px[node], jy = py[node], jz = pz[node], jw = pw[node];
        const float sqj = jx*jx + jy*jy + jz*jz + jw*jw;
        const float dot = tx*jx + ty*jy + tz*jz + tw*jw;
        const float d2  = sqt + sqj - 2.0f * dot;
        unsigned u = __float_as_uint(d2);
        u = (u & 0x80000000u) ? ~u : (u | 0x80000000u);   // monotonic map
        d2m[j] = (node == tl) ? 0xFFFFFFFFu : u;          // exclude self
    }

    unsigned V = 0;
    for (int b = 31; b >= 0; --b) {
        const unsigned test = V | (1u << b);
        int c = 0;
        #pragma unroll
        for (int j = 0; j < 8; j++) c += (d2m[j] < test) ? 1 : 0;
        if (wave_count_sum(c) < KNN) V = test;
    }

    int c = 0;
    #pragma unroll
    for (int j = 0; j < 8; j++) c += (d2m[j] < V) ? 1 : 0;
    const int n_lt = wave_count_sum(c);
    const int need = KNN - n_lt;

    const int woff = wv * 128;
    int cnt_total = 0, taken = 0;
    #pragma unroll
    for (int j = 0; j < 8; j++) {
        const bool lt = d2m[j] < V;
        const bool eq = d2m[j] == V;
        const unsigned long long meq = __ballot(eq);
        const bool sel = lt || (eq && (taken + lanes_below(meq)) < need);
        taken += (int)__popcll(meq);
        const unsigned long long msel = __ballot(sel);
        if (sel) {
            const int pos = cnt_total + lanes_below(msel);
            skey[woff + pos] = ((unsigned long long)d2m[j] << 32)
                             | (unsigned)(base + j * 64 + lane);
        }
        cnt_total += (int)__popcll(msel);
    }
    for (int i = KNN + lane; i < 128; i += 64) skey[woff + i] = ~0ULL;
    __syncthreads();

    for (int kk = 2; kk <= 128; kk <<= 1) {
        for (int jj = kk >> 1; jj >= 1; jj >>= 1) {
            const int i  = ((lane & ~(jj - 1)) << 1) | (lane & (jj - 1));
            const int ix = i | jj;
            const unsigned long long a = skey[woff + i];
            const unsigned long long b = skey[woff + ix];
            const bool up = ((i & kk) == 0);
            if ((a > b) == up) { skey[woff + i] = b; skey[woff + ix] = a; }
            __syncthreads();
        }
    }

    if (lane < KNN)      nbr[t * KNN + lane]      = (int)(unsigned)skey[woff + lane];
    if (lane + 64 < KNN) nbr[t * KNN + lane + 64] = (int)(unsigned)skey[woff + lane + 64];
}

// ---------------------------------------------------------------------------
// prop6: 8 lanes per node, 10 neighbors each, shuffle-reduce. Grid = 256.
// ---------------------------------------------------------------------------
__global__ __launch_bounds__(256) void prop6(const float* __restrict__ hin,
                                             const int* __restrict__ nbr,
                                             float* __restrict__ hout) {
    const int gid = blockIdx.x * 256 + threadIdx.x;
    const int t   = gid >> 3;
    const int sl  = gid & 7;
    const int* nb = nbr + t * KNN + sl * 10;

    float a[F0] = {0.f, 0.f, 0.f, 0.f, 0.f, 0.f};
    #pragma unroll
    for (int j = 0; j < 10; j++) {
        const float* r = hin + (size_t)nb[j] * F0;
        #pragma unroll
        for (int f = 0; f < F0; f++) a[f] += r[f];
    }
    #pragma unroll
    for (int off = 1; off < 8; off <<= 1)
        #pragma unroll
        for (int f = 0; f < F0; f++) a[f] += __shfl_xor(a[f], off);

    if (sl == 0) {
        const float inv = 1.0f / 80.0f;
        float* o = hout + (size_t)t * F0;
        #pragma unroll
        for (int f = 0; f < F0; f++) o[f] = a[f] * inv;
    }
}

// ---------------------------------------------------------------------------
// prop2x v2: BOTH hops fused, gathers from LDS in SoA layout b[4][512].
// R11's [512][4] layout put random rows in bank-quad r%8 (8-way conflict,
// 5.2M conflicts, 45 us). SoA scalar reads land at bank r%32 -> random
// indices spread over all 32 banks (~2 lanes/bank = free, m136).
// Block = (graph, 4-col chunk); grid = 512, XCD-swizzled (2 graphs/XCD).
// ---------------------------------------------------------------------------
__global__ __launch_bounds__(256) void prop2x(const float* __restrict__ H,
                                              const int* __restrict__ nbr,
                                              float* __restrict__ y1,
                                              float* __restrict__ y2) {
    __shared__ float b0[4][NPG];
    __shared__ float b1[4][NPG];
    const int bid  = blockIdx.x;          // 0..511
    const int slot = bid & 7;
    const int idx  = bid >> 3;            // 0..63
    const int g    = slot + (idx >> 5) * 8;   // graph, 2 per XCD
    const int cc   = idx & 31;            // col chunk
    const int c0   = cc * 4;
    const int tid  = threadIdx.x;
    const int base = g << 9;
    const float inv = 1.0f / 80.0f;

    for (int r = tid; r < NPG; r += 256) {
        const float4 v = *(const float4*)(H + (size_t)(base + r) * HID + c0);
        b0[0][r] = v.x; b0[1][r] = v.y; b0[2][r] = v.z; b0[3][r] = v.w;
    }
    __syncthreads();

    // hop1: read b0, write b1 + y1 (thread owns rows tid, tid+256)
    #pragma unroll
    for (int rr = 0; rr < 2; rr++) {
        const int r = tid + rr * 256;
        const int* nb = nbr + (size_t)(base + r) * KNN;
        float a0=0.f,a1=0.f,a2=0.f,a3=0.f;
        for (int i = 0; i < KNN; i += 8) {
            const int4 qa = *(const int4*)(nb + i);
            const int4 qb = *(const int4*)(nb + i + 4);
            const int i0=qa.x&511, i1=qa.y&511, i2=qa.z&511, i3=qa.w&511;
            const int i4=qb.x&511, i5=qb.y&511, i6=qb.z&511, i7=qb.w&511;
            a0 += (b0[0][i0]+b0[0][i1])+(b0[0][i2]+b0[0][i3])
                + (b0[0][i4]+b0[0][i5])+(b0[0][i6]+b0[0][i7]);
            a1 += (b0[1][i0]+b0[1][i1])+(b0[1][i2]+b0[1][i3])
                + (b0[1][i4]+b0[1][i5])+(b0[1][i6]+b0[1][i7]);
            a2 += (b0[2][i0]+b0[2][i1])+(b0[2][i2]+b0[2][i3])
                + (b0[2][i4]+b0[2][i5])+(b0[2][i6]+b0[2][i7]);
            a3 += (b0[3][i0]+b0[3][i1])+(b0[3][i2]+b0[3][i3])
                + (b0[3][i4]+b0[3][i5])+(b0[3][i6]+b0[3][i7]);
        }
        a0 *= inv; a1 *= inv; a2 *= inv; a3 *= inv;
        b1[0][r] = a0; b1[1][r] = a1; b1[2][r] = a2; b1[3][r] = a3;
        float4 o; o.x=a0; o.y=a1; o.z=a2; o.w=a3;
        *(float4*)(y1 + (size_t)(base + r) * HID + c0) = o;
    }
    __syncthreads();

    // hop2: read b1, write y2
    #pragma unroll
    for (int rr = 0; rr < 2; rr++) {
        const int r = tid + rr * 256;
        const int* nb = nbr + (size_t)(base + r) * KNN;
        float a0=0.f,a1=0.f,a2=0.f,a3=0.f;
        for (int i = 0; i < KNN; i += 8) {
            const int4 qa = *(const int4*)(nb + i);
            const int4 qb = *(const int4*)(nb + i + 4);
            const int i0=qa.x&511, i1=qa.y&511, i2=qa.z&511, i3=qa.w&511;
            const int i4=qb.x&511, i5=qb.y&511, i6=qb.z&511, i7=qb.w&511;
            a0 += (b1[0][i0]+b1[0][i1])+(b1[0][i2]+b1[0][i3])
                + (b1[0][i4]+b1[0][i5])+(b1[0][i6]+b1[0][i7]);
            a1 += (b1[1][i0]+b1[1][i1])+(b1[1][i2]+b1[1][i3])
                + (b1[1][i4]+b1[1][i5])+(b1[1][i6]+b1[1][i7]);
            a2 += (b1[2][i0]+b1[2][i1])+(b1[2][i2]+b1[2][i3])
                + (b1[2][i4]+b1[2][i5])+(b1[2][i6]+b1[2][i7]);
            a3 += (b1[3][i0]+b1[3][i1])+(b1[3][i2]+b1[3][i3])
                + (b1[3][i4]+b1[3][i5])+(b1[3][i6]+b1[3][i7]);
        }
        float4 o; o.x=a0*inv; o.y=a1*inv; o.z=a2*inv; o.w=a3*inv;
        *(float4*)(y2 + (size_t)(base + r) * HID + c0) = o;
    }
}

// ---------------------------------------------------------------------------
// Fused TAGConv combine as LDS-tiled GEMM (16 rows x 128 cols per block)
// + fused partial mean/max pool into per-conv psum/pmax buffers.
// ---------------------------------------------------------------------------
template<int K>
__global__ __launch_bounds__(256) void combine_kernel(const float* __restrict__ X,
                                                      const float* __restrict__ Y1,
                                                      const float* __restrict__ Y2,
                                                      const float* __restrict__ W,
                                                      const float* __restrict__ bias,
                                                      float* __restrict__ out,
                                                      float* __restrict__ psum,
                                                      float* __restrict__ pmax) {
    __shared__ float xs[3][RPB * K];
    const int tid  = threadIdx.x;
    const int row0 = blockIdx.x * RPB;

    {
        const float* s0 = X  + (size_t)row0 * K;
        const float* s1 = Y1 + (size_t)row0 * K;
        const float* s2 = Y2 + (size_t)row0 * K;
        if constexpr ((K & 3) == 0) {
            constexpr int NV = RPB * K / 4;
            for (int i = tid; i < NV; i += 256) ((float4*)xs[0])[i] = ((const float4*)s0)[i];
            for (int i = tid; i < NV; i += 256) ((float4*)xs[1])[i] = ((const float4*)s1)[i];
            for (int i = tid; i < NV; i += 256) ((float4*)xs[2])[i] = ((const float4*)s2)[i];
        } else {
            for (int i = tid; i < RPB * K; i += 256) xs[0][i] = s0[i];
            for (int i = tid; i < RPB * K; i += 256) xs[1][i] = s1[i];
            for (int i = tid; i < RPB * K; i += 256) xs[2][i] = s2[i];
        }
    }
    __syncthreads();

    const int c  = tid & 127;
    const int r0 = (tid >> 7) * 8;      // 0 or 8

    float acc[8];
    #pragma unroll
    for (int r = 0; r < 8; r++) acc[r] = 0.0f;

    #pragma unroll
    for (int s = 0; s < 3; s++) {
        const float* __restrict__ Ws   = W + (size_t)s * K * HID;
        const float* __restrict__ xseg = xs[s] + r0 * K;
        for (int k = 0; k < K; k += 2) {
            const float w0 = Ws[(size_t)k * HID + c];
            const float w1 = Ws[(size_t)(k + 1) * HID + c];
            #pragma unroll
            for (int r = 0; r < 8; r++)
                acc[r] += xseg[r * K + k] * w0 + xseg[r * K + k + 1] * w1;
        }
    }

    const float bb = bias[c];
    float sum8 = 0.0f, mx8 = -3.402823e38f;
    #pragma unroll
    for (int r = 0; r < 8; r++) {
        const float v = leaky(acc[r] + bb);
        out[(size_t)(row0 + r0 + r) * HID + c] = v;
        sum8 += v;
        mx8 = fmaxf(mx8, v);
    }

    __shared__ float ssum[128], smx[128];
    if (r0) { ssum[c] = sum8; smx[c] = mx8; }
    __syncthreads();
    if (!r0) {
        psum[(size_t)blockIdx.x * HID + c] = sum8 + ssum[c];
        pmax[(size_t)blockIdx.x * HID + c] = fmaxf(mx8, smx[c]);
    }
}

// ---------------------------------------------------------------------------
// lin0: reduces all three convs' pool partials (32/graph each) into gs[768],
// applies BN, then layer-0 GEMM. Grid = 96 blocks.
// ---------------------------------------------------------------------------
__global__ __launch_bounds__(256) void lin0_kernel(const float* __restrict__ psum1,
                                                   const float* __restrict__ pmax1,
                                                   const float* __restrict__ psum2,
                                                   const float* __restrict__ pmax2,
                                                   const float* __restrict__ psum3,
                                                   const float* __restrict__ pmax3,
                                                   const float* __restrict__ gamma,
                                                   const float* __restrict__ beta,
                                                   const float* __restrict__ mean,
                                                   const float* __restrict__ var,
                                                   const float* __restrict__ W,
                                                   const float* __restrict__ bias,
                                                   float* __restrict__ gout) {
    const int r   = blockIdx.x / 6;
    const int cc  = blockIdx.x % 6;
    const int tid = threadIdx.x;

    __shared__ float gs[H6];
    {   // task 1: conv1 (tid>>7==0) or conv2 (tid>>7==1)
        const int cv = tid >> 7;
        const int c  = tid & 127;
        const float* ps = (cv ? psum2 : psum1) + (size_t)r * BPGR * HID + c;
        const float* pm = (cv ? pmax2 : pmax1) + (size_t)r * BPGR * HID + c;
        float s = 0.0f, m = -3.402823e38f;
        #pragma unroll 8
        for (int b = 0; b < BPGR; b++) { s += ps[b * HID]; m = fmaxf(m, pm[b * HID]); }
        gs[cv * 256 + c]       = s * (1.0f / 512.0f);
        gs[cv * 256 + 128 + c] = m;
    }
    if (tid < 128) {  // task 2: conv3
        const float* ps = psum3 + (size_t)r * BPGR * HID + tid;
        const float* pm = pmax3 + (size_t)r * BPGR * HID + tid;
        float s = 0.0f, m = -3.402823e38f;
        #pragma unroll 8
        for (int b = 0; b < BPGR; b++) { s += ps[b * HID]; m = fmaxf(m, pm[b * HID]); }
        gs[512 + tid]       = s * (1.0f / 512.0f);
        gs[512 + 128 + tid] = m;
    }
    __syncthreads();
    for (int k = tid; k < H6; k += 256)
        gs[k] = (gs[k] - mean[k]) * (1.0f / sqrtf(var[k] + 1e-5f)) * gamma[k] + beta[k];
    __syncthreads();

    const int c  = cc * 128 + (tid & 127);
    const int kh = tid >> 7;
    const int kb = kh * 384;
    float a0=0.f,a1=0.f,a2=0.f,a3=0.f;
    for (int k = kb; k < kb + 384; k += 4) {
        a0 += gs[k]     * W[(size_t)(k)     * H6 + c];
        a1 += gs[k + 1] * W[(size_t)(k + 1) * H6 + c];
        a2 += gs[k + 2] * W[(size_t)(k + 2) * H6 + c];
        a3 += gs[k + 3] * W[(size_t)(k + 3) * H6 + c];
    }
    __shared__ float part[256];
    part[tid] = (a0 + a1) + (a2 + a3);
    __syncthreads();
    if (kh == 0) {
        const float v = part[tid] + part[tid + 128] + bias[c];
        gout[(size_t)r * H6 + c] = leaky(v);
    }
}

// ---------------------------------------------------------------------------
__global__ __launch_bounds__(256) void lin_kernel(const float* __restrict__ gin,
                                                  const float* __restrict__ W,
                                                  const float* __restrict__ bias,
                                                  float* __restrict__ gout) {
    const int r   = blockIdx.x / 6;
    const int cc  = blockIdx.x % 6;
    const int tid = threadIdx.x;

    __shared__ float gs[H6];
    for (int k = tid; k < H6; k += 256) gs[k] = gin[(size_t)r * H6 + k];
    __syncthreads();

    const int c  = cc * 128 + (tid & 127);
    const int kh = tid >> 7;
    const int kb = kh * 384;
    float a0=0.f,a1=0.f,a2=0.f,a3=0.f;
    for (int k = kb; k < kb + 384; k += 4) {
        a0 += gs[k]     * W[(size_t)(k)     * H6 + c];
        a1 += gs[k + 1] * W[(size_t)(k + 1) * H6 + c];
        a2 += gs[k + 2] * W[(size_t)(k + 2) * H6 + c];
        a3 += gs[k + 3] * W[(size_t)(k + 3) * H6 + c];
    }
    __shared__ float part[256];
    part[tid] = (a0 + a1) + (a2 + a3);
    __syncthreads();
    if (kh == 0) {
        const float v = part[tid] + part[tid + 128] + bias[c];
        gout[(size_t)r * H6 + c] = leaky(v);
    }
}

__global__ void out_kernel(const float* __restrict__ gin,
                           const float* __restrict__ W,
                           const float* __restrict__ bias,
                           float* __restrict__ out) {
    const int tid = threadIdx.x;
    __shared__ float part[192];
    if (tid < 192) {
        const int q  = tid >> 2;        // 0..47
        const int r  = q / 3, c = q % 3;
        const int kq = tid & 3;
        float acc = 0.0f;
        for (int k = kq * 192; k < kq * 192 + 192; k++)
            acc += gin[(size_t)r * H6 + k] * W[(size_t)k * 3 + c];
        part[tid] = acc;
    }
    __syncthreads();
    if (tid < 48) {
        const int r = tid / 3, c = tid % 3;
        out[r * 3 + c] = part[tid*4] + part[tid*4+1] + part[tid*4+2] + part[tid*4+3] + bias[c];
    }
}

// ---------------------------------------------------------------------------
extern "C" void kernel_launch(void* const* d_in, const int* in_sizes, int n_in,
                              void* d_out, int out_size, void* d_ws, size_t ws_size,
                              hipStream_t stream) {
    const float* x        = (const float*)d_in[0];
    const float* conv1_w  = (const float*)d_in[2];
    const float* conv1_b  = (const float*)d_in[3];
    const float* conv2_w  = (const float*)d_in[4];
    const float* conv2_b  = (const float*)d_in[5];
    const float* conv3_w  = (const float*)d_in[6];
    const float* conv3_b  = (const float*)d_in[7];
    const float* bn_gamma = (const float*)d_in[8];
    const float* bn_beta  = (const float*)d_in[9];
    const float* bn_mean  = (const float*)d_in[10];
    const float* bn_var   = (const float*)d_in[11];
    const float* lin_w    = (const float*)d_in[12];
    const float* lin_b    = (const float*)d_in[13];
    const float* out_w    = (const float*)d_in[14];
    const float* out_b    = (const float*)d_in[15];

    char* ws = (char*)d_ws;
    size_t off = 0;
    auto alloc = [&](size_t bytes) {
        void* p = ws + off;
        off += (bytes + 255) & ~(size_t)255;
        return p;
    };
    int*   nbr   = (int*)  alloc((size_t)N * KNN * 4);
    float* y6a   = (float*)alloc((size_t)N * F0 * 4);
    float* y6b   = (float*)alloc((size_t)N * F0 * 4);
    float* hA    = (float*)alloc((size_t)N * HID * 4);
    float* hB    = (float*)alloc((size_t)N * HID * 4);
    float* y1    = (float*)alloc((size_t)N * HID * 4);
    float* y2    = (float*)alloc((size_t)N * HID * 4);
    float* ga    = (float*)alloc((size_t)NG * H6 * 4);
    float* gb    = (float*)alloc((size_t)NG * H6 * 4);
    float* psum1 = (float*)alloc((size_t)(N / RPB) * HID * 4);
    float* pmax1 = (float*)alloc((size_t)(N / RPB) * HID * 4);
    float* psum2 = (float*)alloc((size_t)(N / RPB) * HID * 4);
    float* pmax2 = (float*)alloc((size_t)(N / RPB) * HID * 4);
    float* psum3 = (float*)alloc((size_t)(N / RPB) * HID * 4);
    float* pmax3 = (float*)alloc((size_t)(N / RPB) * HID * 4);

    knn_kernel<<<N / 4, 256, 0, stream>>>(x, nbr);

    // conv1 (K=6)
    prop6<<<N * 8 / 256, 256, 0, stream>>>(x, nbr, y6a);
    prop6<<<N * 8 / 256, 256, 0, stream>>>(y6a, nbr, y6b);
    combine_kernel<6><<<N / RPB, 256, 0, stream>>>(x, y6a, y6b, conv1_w, conv1_b, hA, psum1, pmax1);

    // conv2 (K=128): both hops in one launch, SoA-LDS gather (bank-safe)
    prop2x<<<NG * 32, 256, 0, stream>>>(hA, nbr, y1, y2);
    combine_kernel<128><<<N / RPB, 256, 0, stream>>>(hA, y1, y2, conv2_w, conv2_b, hB, psum2, pmax2);

    // conv3 (K=128)
    prop2x<<<NG * 32, 256, 0, stream>>>(hB, nbr, y1, y2);
    combine_kernel<128><<<N / RPB, 256, 0, stream>>>(hB, y1, y2, conv3_w, conv3_b, hA, psum3, pmax3);

    // head: lin0 (pool-reduce + BN fused) + 4 lin + out — 96-block structure.
    // LESSON (R7 conv1_fused, R9 head_kernel): never shrink grid <96 blocks
    // unless per-block memory footprint is trivial. LESSON (R11->R15): random
    // LDS gathers need SoA/scalar layout (bank = r%32), not 16B rows (r%8).
    lin0_kernel<<<96, 256, 0, stream>>>(psum1, pmax1, psum2, pmax2, psum3, pmax3,
                                        bn_gamma, bn_beta, bn_mean, bn_var,
                                        lin_w + 0 * H6 * H6, lin_b + 0 * H6, gb);
    lin_kernel<<<96, 256, 0, stream>>>(gb, lin_w + 1 * H6 * H6, lin_b + 1 * H6, ga);
    lin_kernel<<<96, 256, 0, stream>>>(ga, lin_w + 2 * H6 * H6, lin_b + 2 * H6, gb);
    lin_kernel<<<96, 256, 0, stream>>>(gb, lin_w + 3 * H6 * H6, lin_b + 3 * H6, ga);
    lin_kernel<<<96, 256, 0, stream>>>(ga, lin_w + 4 * H6 * H6, lin_b + 4 * H6, gb);
    out_kernel<<<1, 256, 0, stream>>>(gb, out_w, out_b, (float*)d_out);
}

// Round 16
// 248.212 us; speedup vs baseline: 1.1632x; 1.1632x over previous
//
#include <hip/hip_runtime.h>

constexpr int N    = 8192;
constexpr int NPG  = 512;   // nodes per graph
constexpr int NG   = 16;
constexpr int KNN  = 80;
constexpr int F0   = 6;
constexpr int HID  = 128;
constexpr int H6   = 768;
constexpr int RPB  = 16;    // rows per combine block
constexpr int BPGR = NPG / RPB;  // combine blocks per graph = 32

// UNIFORM graph->XCD mapping: graph g is always processed by blocks whose
// dispatch slot (blockIdx.x & 7) == g & 7, in EVERY kernel (writers AND
// readers). R15 diagnosis: mixed mappings caused cross-XCD dirty-L2
// transfers at ~600-980 GB/s on nbr/h/y buffers.

__device__ __forceinline__ float leaky(float v) { return v > 0.0f ? v : 0.01f * v; }

__device__ __forceinline__ int lanes_below(unsigned long long m) {
    return __builtin_amdgcn_mbcnt_hi((unsigned)(m >> 32),
           __builtin_amdgcn_mbcnt_lo((unsigned)m, 0));
}

// wave-sum of a per-lane count in [0,8] via 4 ballots (result uniform)
__device__ __forceinline__ int wave_count_sum(int c) {
    int total = 0;
    #pragma unroll
    for (int b = 0; b < 4; b++)
        total += (int)__popcll(__ballot((c >> b) & 1)) << b;
    return total;
}

// ---------------------------------------------------------------------------
// KNN, wave-per-target (see R2 notes). Grid 2048, XCD-mapped: graph g's
// blocks land on XCD g&7 so nbr rows are written to that XCD's L2.
// ---------------------------------------------------------------------------
__global__ __launch_bounds__(256) void knn_kernel(const float* __restrict__ x,
                                                  int* __restrict__ nbr) {
    const int bid   = blockIdx.x;
    const int slot  = bid & 7;
    const int idx   = bid >> 3;                 // 0..255
    const int g     = slot + 8 * (idx >> 7);    // graph, 2 per XCD
    const int chunk = idx & 127;                // 128 chunks of 4 targets
    const int tid  = threadIdx.x;
    const int lane = tid & 63;
    const int wv   = tid >> 6;
    const int base = g << 9;
    const int tl   = chunk * 4 + wv;
    const int t    = base + tl;

    __shared__ float px[512], py[512], pz[512], pw[512];
    __shared__ unsigned long long skey[4 * 128];

    for (int j = tid; j < 512; j += 256) {
        const float* row = x + (size_t)(base + j) * F0;
        const float2 ra = *(const float2*)(row);
        const float2 rb = *(const float2*)(row + 2);
        px[j] = ra.x; py[j] = ra.y; pz[j] = rb.x; pw[j] = rb.y;
    }
    __syncthreads();

    const float tx = px[tl], ty = py[tl], tz = pz[tl], tw = pw[tl];
    const float sqt = tx*tx + ty*ty + tz*tz + tw*tw;

    unsigned d2m[8];
    #pragma unroll
    for (int j = 0; j < 8; j++) {
        const int node = j * 64 + lane;
        const float jx = px[node], jy = py[node], jz = pz[node], jw = pw[node];
        const float sqj = jx*jx + jy*jy + jz*jz + jw*jw;
        const float dot = tx*jx + ty*jy + tz*jz + tw*jw;
        const float d2  = sqt + sqj - 2.0f * dot;
        unsigned u = __float_as_uint(d2);
        u = (u & 0x80000000u) ? ~u : (u | 0x80000000u);   // monotonic map
        d2m[j] = (node == tl) ? 0xFFFFFFFFu : u;          // exclude self
    }

    unsigned V = 0;
    for (int b = 31; b >= 0; --b) {
        const unsigned test = V | (1u << b);
        int c = 0;
        #pragma unroll
        for (int j = 0; j < 8; j++) c += (d2m[j] < test) ? 1 : 0;
        if (wave_count_sum(c) < KNN) V = test;
    }

    int c = 0;
    #pragma unroll
    for (int j = 0; j < 8; j++) c += (d2m[j] < V) ? 1 : 0;
    const int n_lt = wave_count_sum(c);
    const int need = KNN - n_lt;

    const int woff = wv * 128;
    int cnt_total = 0, taken = 0;
    #pragma unroll
    for (int j = 0; j < 8; j++) {
        const bool lt = d2m[j] < V;
        const bool eq = d2m[j] == V;
        const unsigned long long meq = __ballot(eq);
        const bool sel = lt || (eq && (taken + lanes_below(meq)) < need);
        taken += (int)__popcll(meq);
        const unsigned long long msel = __ballot(sel);
        if (sel) {
            const int pos = cnt_total + lanes_below(msel);
            skey[woff + pos] = ((unsigned long long)d2m[j] << 32)
                             | (unsigned)(base + j * 64 + lane);
        }
        cnt_total += (int)__popcll(msel);
    }
    for (int i = KNN + lane; i < 128; i += 64) skey[woff + i] = ~0ULL;
    __syncthreads();

    for (int kk = 2; kk <= 128; kk <<= 1) {
        for (int jj = kk >> 1; jj >= 1; jj >>= 1) {
            const int i  = ((lane & ~(jj - 1)) << 1) | (lane & (jj - 1));
            const int ix = i | jj;
            const unsigned long long a = skey[woff + i];
            const unsigned long long b = skey[woff + ix];
            const bool up = ((i & kk) == 0);
            if ((a > b) == up) { skey[woff + i] = b; skey[woff + ix] = a; }
            __syncthreads();
        }
    }

    if (lane < KNN)      nbr[t * KNN + lane]      = (int)(unsigned)skey[woff + lane];
    if (lane + 64 < KNN) nbr[t * KNN + lane + 64] = (int)(unsigned)skey[woff + lane + 64];
}

// ---------------------------------------------------------------------------
// prop6: 8 lanes per node, 10 neighbors each, shuffle-reduce. Grid = 256,
// XCD-mapped (16 blocks/graph on XCD g&7).
// ---------------------------------------------------------------------------
__global__ __launch_bounds__(256) void prop6(const float* __restrict__ hin,
                                             const int* __restrict__ nbr,
                                             float* __restrict__ hout) {
    const int bid   = blockIdx.x;
    const int slot  = bid & 7;
    const int idx   = bid >> 3;                 // 0..31
    const int g     = slot + 8 * (idx >> 4);    // graph
    const int chunk = idx & 15;                 // 16 chunks of 32 nodes
    const int t     = (g << 9) + chunk * 32 + (threadIdx.x >> 3);
    const int sl    = threadIdx.x & 7;
    const int* nb   = nbr + t * KNN + sl * 10;

    float a[F0] = {0.f, 0.f, 0.f, 0.f, 0.f, 0.f};
    #pragma unroll
    for (int j = 0; j < 10; j++) {
        const float* r = hin + (size_t)nb[j] * F0;
        #pragma unroll
        for (int f = 0; f < F0; f++) a[f] += r[f];
    }
    #pragma unroll
    for (int off = 1; off < 8; off <<= 1)
        #pragma unroll
        for (int f = 0; f < F0; f++) a[f] += __shfl_xor(a[f], off);

    if (sl == 0) {
        const float inv = 1.0f / 80.0f;
        float* o = hout + (size_t)t * F0;
        #pragma unroll
        for (int f = 0; f < F0; f++) o[f] = a[f] * inv;
    }
}

// ---------------------------------------------------------------------------
// prop128: Y[t] = (1/80)*sum H[nbr]. 256-thread blocks (8 targets), grid
// 1024, XCD-mapped.
// ---------------------------------------------------------------------------
__global__ __launch_bounds__(256) void prop128(const float* __restrict__ hin,
                                               const int* __restrict__ nbr,
                                               float* __restrict__ hout) {
    const int bid   = blockIdx.x;
    const int slot  = bid & 7;
    const int g     = slot + (bid >> 9) * 8;     // graph (16 total, 2 per XCD)
    const int chunk = (bid >> 3) & 63;           // 64 chunks of 8 targets
    const int lane  = threadIdx.x & 31;
    const int t     = (g << 9) + chunk * 8 + (threadIdx.x >> 5);
    const int* nb   = nbr + t * KNN;
    float a0=0.f,a1=0.f,a2=0.f,a3=0.f;
    for (int i = 0; i < KNN; i += 16) {
        const int4 sA = *(const int4*)(nb + i);
        const int4 sB = *(const int4*)(nb + i + 4);
        const int4 sC = *(const int4*)(nb + i + 8);
        const int4 sD = *(const int4*)(nb + i + 12);
        const int idx[16] = {sA.x,sA.y,sA.z,sA.w, sB.x,sB.y,sB.z,sB.w,
                             sC.x,sC.y,sC.z,sC.w, sD.x,sD.y,sD.z,sD.w};
        float4 v[16];
        #pragma unroll
        for (int q = 0; q < 16; q++)
            v[q] = *(const float4*)(hin + (size_t)idx[q] * HID + lane * 4);
        #pragma unroll
        for (int q = 0; q < 16; q += 4) {
            a0 += (v[q].x + v[q+1].x) + (v[q+2].x + v[q+3].x);
            a1 += (v[q].y + v[q+1].y) + (v[q+2].y + v[q+3].y);
            a2 += (v[q].z + v[q+1].z) + (v[q+2].z + v[q+3].z);
            a3 += (v[q].w + v[q+1].w) + (v[q+2].w + v[q+3].w);
        }
    }
    const float inv = 1.0f / 80.0f;
    float4 r; r.x=a0*inv; r.y=a1*inv; r.z=a2*inv; r.w=a3*inv;
    *(float4*)(hout + (size_t)t * HID + lane * 4) = r;
}

// ---------------------------------------------------------------------------
// combine6: LDS-tiled GEMM for conv1 (K=6) + fused partial pool.
// XCD-mapped; psum/pmax indexed by canonical tile id.
// ---------------------------------------------------------------------------
__global__ __launch_bounds__(256) void combine6(const float* __restrict__ X,
                                                const float* __restrict__ Y1,
                                                const float* __restrict__ Y2,
                                                const float* __restrict__ W,
                                                const float* __restrict__ bias,
                                                float* __restrict__ out,
                                                float* __restrict__ psum,
                                                float* __restrict__ pmax) {
    constexpr int K = F0;
    __shared__ float xs[3][RPB * K];
    const int bid   = blockIdx.x;               // 0..511
    const int slot  = bid & 7;
    const int idx   = bid >> 3;                 // 0..63
    const int g     = slot + 8 * (idx >> 5);
    const int tile  = g * BPGR + (idx & 31);    // canonical tile id
    const int row0  = tile * RPB;
    const int tid   = threadIdx.x;

    for (int i = tid; i < RPB * K; i += 256) xs[0][i] = X [(size_t)row0 * K + i];
    for (int i = tid; i < RPB * K; i += 256) xs[1][i] = Y1[(size_t)row0 * K + i];
    for (int i = tid; i < RPB * K; i += 256) xs[2][i] = Y2[(size_t)row0 * K + i];
    __syncthreads();

    const int c  = tid & 127;
    const int r0 = (tid >> 7) * 8;

    float acc[8];
    #pragma unroll
    for (int r = 0; r < 8; r++) acc[r] = 0.0f;

    #pragma unroll
    for (int s = 0; s < 3; s++) {
        const float* __restrict__ Ws   = W + (size_t)s * K * HID;
        const float* __restrict__ xseg = xs[s] + r0 * K;
        #pragma unroll
        for (int k = 0; k < K; k++) {
            const float w0 = Ws[(size_t)k * HID + c];
            #pragma unroll
            for (int r = 0; r < 8; r++)
                acc[r] += xseg[r * K + k] * w0;
        }
    }

    const float bb = bias[c];
    float sum8 = 0.0f, mx8 = -3.402823e38f;
    #pragma unroll
    for (int r = 0; r < 8; r++) {
        const float v = leaky(acc[r] + bb);
        out[(size_t)(row0 + r0 + r) * HID + c] = v;
        sum8 += v;
        mx8 = fmaxf(mx8, v);
    }

    __shared__ float ssum[128], smx[128];
    if (r0) { ssum[c] = sum8; smx[c] = mx8; }
    __syncthreads();
    if (!r0) {
        psum[(size_t)tile * HID + c] = sum8 + ssum[c];
        pmax[(size_t)tile * HID + c] = fmaxf(mx8, smx[c]);
    }
}

// ---------------------------------------------------------------------------
// combine128f: hop2 gather fused into conv GEMM (R13 config, RPB=16).
// XCD-mapped; psum/pmax indexed by canonical tile id.
// ---------------------------------------------------------------------------
__global__ __launch_bounds__(256) void combine128f(const float* __restrict__ X,
                                                   const float* __restrict__ Y1,
                                                   const int* __restrict__ nbr,
                                                   const float* __restrict__ W,
                                                   const float* __restrict__ bias,
                                                   float* __restrict__ out,
                                                   float* __restrict__ psum,
                                                   float* __restrict__ pmax) {
    constexpr int K = HID;
    __shared__ float xs[3][RPB * K];
    const int bid   = blockIdx.x;                // 0..511
    const int slot  = bid & 7;
    const int idx   = bid >> 3;                  // 0..63
    const int g     = slot + (idx >> 5) * 8;     // graph, 2 per XCD
    const int chunk = idx & 31;
    const int tile  = g * BPGR + chunk;          // canonical tile id
    const int row0  = tile * RPB;
    const int tid   = threadIdx.x;

    {   // stage X and Y1 tiles
        const float* s0 = X  + (size_t)row0 * K;
        const float* s1 = Y1 + (size_t)row0 * K;
        constexpr int NV = RPB * K / 4;
        for (int i = tid; i < NV; i += 256) ((float4*)xs[0])[i] = ((const float4*)s0)[i];
        for (int i = tid; i < NV; i += 256) ((float4*)xs[1])[i] = ((const float4*)s1)[i];
    }
    {   // gather Y2 tile: 8 targets in flight x 2 iters, 32 lanes = 128 cols
        const int lane = tid & 31;
        const int w8   = tid >> 5;               // 0..7
        const float inv = 1.0f / 80.0f;
        #pragma unroll
        for (int rr = 0; rr < 2; rr++) {
            const int r = w8 + rr * 8;
            const int* nb = nbr + (size_t)(row0 + r) * KNN;
            float a0=0.f,a1=0.f,a2=0.f,a3=0.f;
            for (int i = 0; i < KNN; i += 16) {
                const int4 sA = *(const int4*)(nb + i);
                const int4 sB = *(const int4*)(nb + i + 4);
                const int4 sC = *(const int4*)(nb + i + 8);
                const int4 sD = *(const int4*)(nb + i + 12);
                const int ix[16] = {sA.x,sA.y,sA.z,sA.w, sB.x,sB.y,sB.z,sB.w,
                                    sC.x,sC.y,sC.z,sC.w, sD.x,sD.y,sD.z,sD.w};
                float4 v[16];
                #pragma unroll
                for (int q = 0; q < 16; q++)
                    v[q] = *(const float4*)(Y1 + (size_t)ix[q] * HID + lane * 4);
                #pragma unroll
                for (int q = 0; q < 16; q += 4) {
                    a0 += (v[q].x + v[q+1].x) + (v[q+2].x + v[q+3].x);
                    a1 += (v[q].y + v[q+1].y) + (v[q+2].y + v[q+3].y);
                    a2 += (v[q].z + v[q+1].z) + (v[q+2].z + v[q+3].z);
                    a3 += (v[q].w + v[q+1].w) + (v[q+2].w + v[q+3].w);
                }
            }
            float4 o; o.x=a0*inv; o.y=a1*inv; o.z=a2*inv; o.w=a3*inv;
            *(float4*)&xs[2][r * K + lane * 4] = o;
        }
    }
    __syncthreads();

    const int c  = tid & 127;
    const int r0 = (tid >> 7) * 8;

    float acc[8];
    #pragma unroll
    for (int r = 0; r < 8; r++) acc[r] = 0.0f;

    #pragma unroll
    for (int s = 0; s < 3; s++) {
        const float* __restrict__ Ws   = W + (size_t)s * K * HID;
        const float* __restrict__ xseg = xs[s] + r0 * K;
        for (int k = 0; k < K; k += 2) {
            const float w0 = Ws[(size_t)k * HID + c];
            const float w1 = Ws[(size_t)(k + 1) * HID + c];
            #pragma unroll
            for (int r = 0; r < 8; r++)
                acc[r] += xseg[r * K + k] * w0 + xseg[r * K + k + 1] * w1;
        }
    }

    const float bb = bias[c];
    float sum8 = 0.0f, mx8 = -3.402823e38f;
    #pragma unroll
    for (int r = 0; r < 8; r++) {
        const float v = leaky(acc[r] + bb);
        out[(size_t)(row0 + r0 + r) * HID + c] = v;
        sum8 += v;
        mx8 = fmaxf(mx8, v);
    }

    __shared__ float ssum[128], smx[128];
    if (r0) { ssum[c] = sum8; smx[c] = mx8; }
    __syncthreads();
    if (!r0) {
        psum[(size_t)tile * HID + c] = sum8 + ssum[c];
        pmax[(size_t)tile * HID + c] = fmaxf(mx8, smx[c]);
    }
}

// ---------------------------------------------------------------------------
// lin0: reduces all three convs' pool partials into gs[768], applies BN,
// then layer-0 GEMM. Grid = 16 rows x 6 col-chunks = 96 blocks.
// ---------------------------------------------------------------------------
__global__ __launch_bounds__(256) void lin0_kernel(const float* __restrict__ psum1,
                                                   const float* __restrict__ pmax1,
                                                   const float* __restrict__ psum2,
                                                   const float* __restrict__ pmax2,
                                                   const float* __restrict__ psum3,
                                                   const float* __restrict__ pmax3,
                                                   const float* __restrict__ gamma,
                                                   const float* __restrict__ beta,
                                                   const float* __restrict__ mean,
                                                   const float* __restrict__ var,
                                                   const float* __restrict__ W,
                                                   const float* __restrict__ bias,
                                                   float* __restrict__ gout) {
    const int r   = blockIdx.x / 6;
    const int cc  = blockIdx.x % 6;
    const int tid = threadIdx.x;

    __shared__ float gs[H6];
    {   // task 1: conv1 (tid>>7==0) or conv2 (tid>>7==1)
        const int cv = tid >> 7;
        const int c  = tid & 127;
        const float* ps = (cv ? psum2 : psum1) + (size_t)r * BPGR * HID + c;
        const float* pm = (cv ? pmax2 : pmax1) + (size_t)r * BPGR * HID + c;
        float s = 0.0f, m = -3.402823e38f;
        #pragma unroll 8
        for (int b = 0; b < BPGR; b++) { s += ps[b * HID]; m = fmaxf(m, pm[b * HID]); }
        gs[cv * 256 + c]       = s * (1.0f / 512.0f);
        gs[cv * 256 + 128 + c] = m;
    }
    if (tid < 128) {  // task 2: conv3
        const float* ps = psum3 + (size_t)r * BPGR * HID + tid;
        const float* pm = pmax3 + (size_t)r * BPGR * HID + tid;
        float s = 0.0f, m = -3.402823e38f;
        #pragma unroll 8
        for (int b = 0; b < BPGR; b++) { s += ps[b * HID]; m = fmaxf(m, pm[b * HID]); }
        gs[512 + tid]       = s * (1.0f / 512.0f);
        gs[512 + 128 + tid] = m;
    }
    __syncthreads();
    for (int k = tid; k < H6; k += 256)
        gs[k] = (gs[k] - mean[k]) * (1.0f / sqrtf(var[k] + 1e-5f)) * gamma[k] + beta[k];
    __syncthreads();

    const int c  = cc * 128 + (tid & 127);
    const int kh = tid >> 7;
    const int kb = kh * 384;
    float a0=0.f,a1=0.f,a2=0.f,a3=0.f;
    for (int k = kb; k < kb + 384; k += 4) {
        a0 += gs[k]     * W[(size_t)(k)     * H6 + c];
        a1 += gs[k + 1] * W[(size_t)(k + 1) * H6 + c];
        a2 += gs[k + 2] * W[(size_t)(k + 2) * H6 + c];
        a3 += gs[k + 3] * W[(size_t)(k + 3) * H6 + c];
    }
    __shared__ float part[256];
    part[tid] = (a0 + a1) + (a2 + a3);
    __syncthreads();
    if (kh == 0) {
        const float v = part[tid] + part[tid + 128] + bias[c];
        gout[(size_t)r * H6 + c] = leaky(v);
    }
}

// ---------------------------------------------------------------------------
__global__ __launch_bounds__(256) void lin_kernel(const float* __restrict__ gin,
                                                  const float* __restrict__ W,
                                                  const float* __restrict__ bias,
                                                  float* __restrict__ gout) {
    const int r   = blockIdx.x / 6;
    const int cc  = blockIdx.x % 6;
    const int tid = threadIdx.x;

    __shared__ float gs[H6];
    for (int k = tid; k < H6; k += 256) gs[k] = gin[(size_t)r * H6 + k];
    __syncthreads();

    const int c  = cc * 128 + (tid & 127);
    const int kh = tid >> 7;
    const int kb = kh * 384;
    float a0=0.f,a1=0.f,a2=0.f,a3=0.f;
    for (int k = kb; k < kb + 384; k += 4) {
        a0 += gs[k]     * W[(size_t)(k)     * H6 + c];
        a1 += gs[k + 1] * W[(size_t)(k + 1) * H6 + c];
        a2 += gs[k + 2] * W[(size_t)(k + 2) * H6 + c];
        a3 += gs[k + 3] * W[(size_t)(k + 3) * H6 + c];
    }
    __shared__ float part[256];
    part[tid] = (a0 + a1) + (a2 + a3);
    __syncthreads();
    if (kh == 0) {
        const float v = part[tid] + part[tid + 128] + bias[c];
        gout[(size_t)r * H6 + c] = leaky(v);
    }
}

__global__ void out_kernel(const float* __restrict__ gin,
                           const float* __restrict__ W,
                           const float* __restrict__ bias,
                           float* __restrict__ out) {
    const int tid = threadIdx.x;
    __shared__ float part[192];
    if (tid < 192) {
        const int q  = tid >> 2;        // 0..47
        const int r  = q / 3, c = q % 3;
        const int kq = tid & 3;
        float acc = 0.0f;
        for (int k = kq * 192; k < kq * 192 + 192; k++)
            acc += gin[(size_t)r * H6 + k] * W[(size_t)k * 3 + c];
        part[tid] = acc;
    }
    __syncthreads();
    if (tid < 48) {
        const int r = tid / 3, c = tid % 3;
        out[r * 3 + c] = part[tid*4] + part[tid*4+1] + part[tid*4+2] + part[tid*4+3] + bias[c];
    }
}

// ---------------------------------------------------------------------------
extern "C" void kernel_launch(void* const* d_in, const int* in_sizes, int n_in,
                              void* d_out, int out_size, void* d_ws, size_t ws_size,
                              hipStream_t stream) {
    const float* x        = (const float*)d_in[0];
    const float* conv1_w  = (const float*)d_in[2];
    const float* conv1_b  = (const float*)d_in[3];
    const float* conv2_w  = (const float*)d_in[4];
    const float* conv2_b  = (const float*)d_in[5];
    const float* conv3_w  = (const float*)d_in[6];
    const float* conv3_b  = (const float*)d_in[7];
    const float* bn_gamma = (const float*)d_in[8];
    const float* bn_beta  = (const float*)d_in[9];
    const float* bn_mean  = (const float*)d_in[10];
    const float* bn_var   = (const float*)d_in[11];
    const float* lin_w    = (const float*)d_in[12];
    const float* lin_b    = (const float*)d_in[13];
    const float* out_w    = (const float*)d_in[14];
    const float* out_b    = (const float*)d_in[15];

    char* ws = (char*)d_ws;
    size_t off = 0;
    auto alloc = [&](size_t bytes) {
        void* p = ws + off;
        off += (bytes + 255) & ~(size_t)255;
        return p;
    };
    int*   nbr   = (int*)  alloc((size_t)N * KNN * 4);
    float* y6a   = (float*)alloc((size_t)N * F0 * 4);
    float* y6b   = (float*)alloc((size_t)N * F0 * 4);
    float* hA    = (float*)alloc((size_t)N * HID * 4);
    float* hB    = (float*)alloc((size_t)N * HID * 4);
    float* y1    = (float*)alloc((size_t)N * HID * 4);
    float* ga    = (float*)alloc((size_t)NG * H6 * 4);
    float* gb    = (float*)alloc((size_t)NG * H6 * 4);
    float* psum1 = (float*)alloc((size_t)(N / RPB) * HID * 4);
    float* pmax1 = (float*)alloc((size_t)(N / RPB) * HID * 4);
    float* psum2 = (float*)alloc((size_t)(N / RPB) * HID * 4);
    float* pmax2 = (float*)alloc((size_t)(N / RPB) * HID * 4);
    float* psum3 = (float*)alloc((size_t)(N / RPB) * HID * 4);
    float* pmax3 = (float*)alloc((size_t)(N / RPB) * HID * 4);

    knn_kernel<<<N / 4, 256, 0, stream>>>(x, nbr);

    // conv1 (K=6)
    prop6<<<N * 8 / 256, 256, 0, stream>>>(x, nbr, y6a);
    prop6<<<N * 8 / 256, 256, 0, stream>>>(y6a, nbr, y6b);
    combine6<<<N / RPB, 256, 0, stream>>>(x, y6a, y6b, conv1_w, conv1_b, hA, psum1, pmax1);

    // conv2 (K=128): hop1 then fused hop2+GEMM, all on graph's home XCD
    prop128<<<N / 8, 256, 0, stream>>>(hA, nbr, y1);
    combine128f<<<N / RPB, 256, 0, stream>>>(hA, y1, nbr, conv2_w, conv2_b, hB, psum2, pmax2);

    // conv3 (K=128)
    prop128<<<N / 8, 256, 0, stream>>>(hB, nbr, y1);
    combine128f<<<N / RPB, 256, 0, stream>>>(hB, y1, nbr, conv3_w, conv3_b, hA, psum3, pmax3);

    // head: lin0 (pool-reduce + BN fused) + 4 lin + out — 96-block structure.
    // LESSONS: (R7/R9) never shrink grid <96 blocks unless per-block memory
    // footprint is trivial; (R11/R15) random LDS gathers conflict-bound;
    // (R16) producers AND consumers of per-graph data must share one
    // graph->XCD mapping or dirty-L2 lines cross XCDs at ~600 GB/s.
    lin0_kernel<<<96, 256, 0, stream>>>(psum1, pmax1, psum2, pmax2, psum3, pmax3,
                                        bn_gamma, bn_beta, bn_mean, bn_var,
                                        lin_w + 0 * H6 * H6, lin_b + 0 * H6, gb);
    lin_kernel<<<96, 256, 0, stream>>>(gb, lin_w + 1 * H6 * H6, lin_b + 1 * H6, ga);
    lin_kernel<<<96, 256, 0, stream>>>(ga, lin_w + 2 * H6 * H6, lin_b + 2 * H6, gb);
    lin_kernel<<<96, 256, 0, stream>>>(gb, lin_w + 3 * H6 * H6, lin_b + 3 * H6, ga);
    lin_kernel<<<96, 256, 0, stream>>>(ga, lin_w + 4 * H6 * H6, lin_b + 4 * H6, gb);
    out_kernel<<<1, 256, 0, stream>>>(gb, out_w, out_b, (float*)d_out);
}